// Round 2
// baseline (112.472 us; speedup 1.0000x reference)
//
#include <hip/hip_runtime.h>

// ALNN layer: B=64, K=13, L=200, D=64, fp32.
// out[b,k,d] = relu( sum_l w_v[k,l,d]*lat + 200*b_v[k,d] )
// lat = relu( wt0*x + wt1*dt + wt2*inten + wt3*m + 4*b_t[k,l,d] )
// inten = relu( x * exp(-relu(alpha[k]) * |t - 4k|) )
//
// Stage 1: block = (k, b-group of 8, l-chunk of 20). Weights in registers,
// reused across 8 batches; float4 loads along d; LDS reduce over l; global
// atomicAdd partials into ws. Stage 2: bias + relu.
// Block order id = k*80 + (lc*8+bg) -> id%8 == bg: all blocks touching one
// b-group's inputs land on one XCD (L2 locality, ~1.6 MB/XCD input slice).

#define NB 64
#define NK 13
#define NL 200
#define ND 64
#define BG 8            // batches per block
#define LC 20           // l-steps per block
#define NLC (NL / LC)   // 10
#define NBG (NB / BG)   // 8

__global__ __launch_bounds__(320) void alnn_stage1(
    const float* __restrict__ X, const float* __restrict__ T,
    const float* __restrict__ M, const float* __restrict__ DT,
    const float* __restrict__ alpha, const float* __restrict__ w_v,
    const float* __restrict__ w_t, const float* __restrict__ b_t,
    float* __restrict__ ws)
{
    const int k   = blockIdx.x / (NBG * NLC);
    const int s   = blockIdx.x % (NBG * NLC);
    const int bg  = s & 7;           // XCD id = blockIdx%8 = bg
    const int lc  = s >> 3;
    const int tid = threadIdx.x;
    const int dq  = tid & 15;        // d-quad index
    const int lsub = tid >> 4;       // 0..19
    const int l   = lc * LC + lsub;
    const int d0  = dq * 4;

    const float a    = fmaxf(alpha[k], 0.0f);
    const float reft = 4.0f * (float)k;    // linspace(0,48,13) step = 4

    // per-(k,l,d0..d0+3) weights -> registers, reused across 8 batches
    const int wd = (k * NL + l) * ND + d0;           // flat [k,l,d] index
    const float4* wt4p = (const float4*)w_t;         // w_t[k,l,d,4]: one float4 per d
    const float4 wtA = wt4p[wd + 0];
    const float4 wtB = wt4p[wd + 1];
    const float4 wtC = wt4p[wd + 2];
    const float4 wtD = wt4p[wd + 3];
    const float4 bt4 = ((const float4*)b_t)[wd >> 2];
    const float4 wv4 = ((const float4*)w_v)[wd >> 2];

    const float4* X4  = (const float4*)X;
    const float4* T4  = (const float4*)T;
    const float4* M4  = (const float4*)M;
    const float4* DT4 = (const float4*)DT;

    float4 acc[BG];

#define COMP(c, wt)  {                                                   \
        const float dist  = fabsf(t4.c - reft);                          \
        const float kern  = __expf(-a * dist);                           \
        const float inten = fmaxf(x4.c * kern, 0.0f);                    \
        const float sf = wt.x * x4.c + wt.y * dt4.c + wt.z * inten +     \
                         wt.w * m4.c + 4.0f * bt4.c;                     \
        acc[b].c = fmaf(wv4.c, fmaxf(sf, 0.0f), acc[b].c);               \
    }

    #pragma unroll 2
    for (int b = 0; b < BG; ++b) {
        const int bi = bg * BG + b;
        const int io = ((bi * NL + l) * ND + d0) >> 2;
        const float4 x4  = X4[io];
        const float4 t4  = T4[io];
        const float4 m4  = M4[io];
        const float4 dt4 = DT4[io];
        acc[b] = make_float4(0.f, 0.f, 0.f, 0.f);
        COMP(x, wtA) COMP(y, wtB) COMP(z, wtC) COMP(w, wtD)
    }
#undef COMP

    // LDS reduction over the 20 l-slices
    __shared__ float red[LC][BG][ND];   // 40 KB
    #pragma unroll
    for (int b = 0; b < BG; ++b)
        *(float4*)&red[lsub][b][d0] = acc[b];
    __syncthreads();

    const float* redf = (const float*)red;
    for (int s2 = tid; s2 < BG * ND; s2 += 320) {
        float sum = 0.0f;
        #pragma unroll
        for (int ls = 0; ls < LC; ++ls)
            sum += redf[ls * (BG * ND) + s2];
        const int b = s2 >> 6;
        const int d = s2 & 63;
        const int bi = bg * BG + b;
        atomicAdd(&ws[(bi * NK + k) * ND + d], sum);
    }
}

__global__ __launch_bounds__(256) void alnn_stage2(
    const float* __restrict__ ws, const float* __restrict__ b_v,
    float* __restrict__ out)
{
    const int idx = blockIdx.x * 256 + threadIdx.x;
    if (idx < NB * NK * ND) {
        const int d = idx & 63;
        const int k = (idx >> 6) % NK;
        out[idx] = fmaxf(ws[idx] + (float)NL * b_v[k * ND + d], 0.0f);
    }
}

extern "C" void kernel_launch(void* const* d_in, const int* in_sizes, int n_in,
                              void* d_out, int out_size, void* d_ws, size_t ws_size,
                              hipStream_t stream) {
    const float* X     = (const float*)d_in[0];
    const float* T     = (const float*)d_in[1];
    const float* M     = (const float*)d_in[2];
    const float* DT    = (const float*)d_in[3];
    const float* alpha = (const float*)d_in[4];
    const float* w_v   = (const float*)d_in[5];
    const float* w_t   = (const float*)d_in[6];
    const float* b_v   = (const float*)d_in[7];
    const float* b_t   = (const float*)d_in[8];
    float* out = (float*)d_out;
    float* ws  = (float*)d_ws;

    hipMemsetAsync(ws, 0, (size_t)NB * NK * ND * sizeof(float), stream);
    alnn_stage1<<<NK * NBG * NLC, 320, 0, stream>>>(X, T, M, DT, alpha, w_v, w_t, b_t, ws);
    alnn_stage2<<<(NB * NK * ND + 255) / 256, 256, 0, stream>>>(ws, b_v, out);
}

// Round 3
// 94.144 us; speedup vs baseline: 1.1947x; 1.1947x over previous
//
#include <hip/hip_runtime.h>

// ALNN layer: B=64, K=13, L=200, D=64, fp32. Single fused kernel.
// out[b,k,d] = relu( sum_l w_v[k,l,d]*lat + 200*b_v[k,d] )
// lat = relu( wt0*x + wt1*dt + wt2*inten + wt3*m + 4*b_t[k,l,d] )
// inten = relu( x * exp(-relu(alpha[k]) * |t - 4k|) )
//
// Block = (k, batch-pair): weights loaded once per block and reused across
// 2 batches in registers. All global loads are float4 along d. L-reduction
// via 8 KB LDS. One launch, no scratch, no atomics.

#define NB 64
#define NK 13
#define NL 200
#define ND 64

__global__ __launch_bounds__(256) void alnn_fused(
    const float* __restrict__ X, const float* __restrict__ T,
    const float* __restrict__ M, const float* __restrict__ DT,
    const float* __restrict__ alpha, const float* __restrict__ w_v,
    const float* __restrict__ w_t, const float* __restrict__ b_v,
    const float* __restrict__ b_t, float* __restrict__ out)
{
    const int k   = blockIdx.x >> 5;      // 0..12
    const int bp  = blockIdx.x & 31;      // batch pair 0..31
    const int tid = threadIdx.x;
    const int dq  = tid & 15;             // d-quad
    const int d0  = dq << 2;
    const int lsub = tid >> 4;            // 0..15

    const float a    = fmaxf(alpha[k], 0.0f);
    const float reft = 4.0f * (float)k;   // linspace(0,48,13) step = 4

    const float4* X4  = (const float4*)X;
    const float4* T4  = (const float4*)T;
    const float4* M4  = (const float4*)M;
    const float4* DT4 = (const float4*)DT;
    const float4* WT4 = (const float4*)w_t;   // [k,l,d] -> one float4 each
    const float4* BT4 = (const float4*)b_t;
    const float4* WV4 = (const float4*)w_v;

    const int b0 = bp << 1;
    const int b1 = b0 + 1;

    float4 acc0 = make_float4(0.f, 0.f, 0.f, 0.f);
    float4 acc1 = make_float4(0.f, 0.f, 0.f, 0.f);

#define COMP(c, wt, acc) {                                                \
        const float dist  = fabsf(t4.c - reft);                           \
        const float kern  = __expf(-a * dist);                            \
        const float inten = fmaxf(x4.c * kern, 0.0f);                     \
        const float sf = wt.x * x4.c + wt.y * dt4.c + wt.z * inten +      \
                         wt.w * m4.c + 4.0f * bt4.c;                      \
        acc.c = fmaf(wv4.c, fmaxf(sf, 0.0f), acc.c);                      \
    }

    #pragma unroll 2
    for (int j = 0; j < 13; ++j) {
        const int l = (j << 4) + lsub;
        if (l < NL) {
            const int wd = (k * NL + l) * ND + d0;   // flat [k,l,d] float index
            const float4 wtA = WT4[wd + 0];
            const float4 wtB = WT4[wd + 1];
            const float4 wtC = WT4[wd + 2];
            const float4 wtD = WT4[wd + 3];
            const float4 bt4 = BT4[wd >> 2];
            const float4 wv4 = WV4[wd >> 2];
            {
                const int io = ((b0 * NL + l) * ND + d0) >> 2;
                const float4 x4  = X4[io];
                const float4 t4  = T4[io];
                const float4 m4  = M4[io];
                const float4 dt4 = DT4[io];
                COMP(x, wtA, acc0) COMP(y, wtB, acc0)
                COMP(z, wtC, acc0) COMP(w, wtD, acc0)
            }
            {
                const int io = ((b1 * NL + l) * ND + d0) >> 2;
                const float4 x4  = X4[io];
                const float4 t4  = T4[io];
                const float4 m4  = M4[io];
                const float4 dt4 = DT4[io];
                COMP(x, wtA, acc1) COMP(y, wtB, acc1)
                COMP(z, wtC, acc1) COMP(w, wtD, acc1)
            }
        }
    }
#undef COMP

    // LDS reduce over the 16 l-slices: red[lsub][b][dq] float4 = 8 KB
    __shared__ float4 red[16][2][16];
    red[lsub][0][dq] = acc0;
    red[lsub][1][dq] = acc1;
    __syncthreads();

    if (tid < 128) {
        const int b = tid >> 6;        // 0..1
        const int d = tid & 63;
        const float* redf = (const float*)red;
        // float address: ls*128 + b*64 + d  (lanes d consecutive: conflict-free)
        float s = 0.0f;
        #pragma unroll
        for (int ls = 0; ls < 16; ++ls)
            s += redf[ls * 128 + b * 64 + d];
        const int bi = b0 + b;
        s += (float)NL * b_v[k * ND + d];
        out[(bi * NK + k) * ND + d] = fmaxf(s, 0.0f);
    }
}

extern "C" void kernel_launch(void* const* d_in, const int* in_sizes, int n_in,
                              void* d_out, int out_size, void* d_ws, size_t ws_size,
                              hipStream_t stream) {
    const float* X     = (const float*)d_in[0];
    const float* T     = (const float*)d_in[1];
    const float* M     = (const float*)d_in[2];
    const float* DT    = (const float*)d_in[3];
    const float* alpha = (const float*)d_in[4];
    const float* w_v   = (const float*)d_in[5];
    const float* w_t   = (const float*)d_in[6];
    const float* b_v   = (const float*)d_in[7];
    const float* b_t   = (const float*)d_in[8];
    float* out = (float*)d_out;

    alnn_fused<<<NK * 32, 256, 0, stream>>>(X, T, M, DT, alpha, w_v, w_t, b_v, b_t, out);
}